// Round 13
// baseline (90.484 us; speedup 1.0000x reference)
//
#include <hip/hip_runtime.h>
#include <math.h>

#define BATCH 8
#define CIN 64
#define COUT 64
#define HH 128
#define WW 128
#define HW (HH*WW)
#define TPX 64       // pixels per block (half row)
#define KDIM 576
#define NR 5         // staged rows  (h-2 .. h+2, clamped)
#define NC 69        // staged cols  (w0-2 .. w0+66, clamped)
#define NSLOT (NR*NC)          // 345 col-slots
#define NITEM (NSLOT*8)        // 2760 16B-chunks

typedef __attribute__((ext_vector_type(8))) short short8;
typedef __attribute__((ext_vector_type(4))) float f32x4;
typedef _Float16 h2   __attribute__((ext_vector_type(2)));
typedef _Float16 h8   __attribute__((ext_vector_type(8)));

__device__ __forceinline__ short f2h(float f) {
    union { _Float16 h; short s; } u;
    u.h = (_Float16)f;
    return u.s;
}

// ---------------- Kernel 1: transpose + weight reorder (merged) ----------------
__global__ void __launch_bounds__(256) prep_kernel(const float* __restrict__ x,
                                                   unsigned short* __restrict__ xT,
                                                   const float* __restrict__ w_dcn,
                                                   const float* __restrict__ w_off,
                                                   unsigned short* __restrict__ wt2,
                                                   unsigned short* __restrict__ wtoff2) {
    if (blockIdx.x < 4096) {
        int idx = blockIdx.x * 256 + threadIdx.x;   // 1,048,576 total
        int c8 = idx & 7;
        int w  = (idx >> 3) & 127;
        int h  = (idx >> 10) & 127;
        int b  = idx >> 17;
        const float* xp = x + (((size_t)(b * 64 + c8 * 8) * 128 + h) * 128 + w);
        short8 o;
#pragma unroll
        for (int j = 0; j < 8; ++j)
            o[j] = f2h(xp[(size_t)j * HW]);
        *(short8*)(xT + (size_t)idx * 8) = o;
        return;
    }
    int gid = (blockIdx.x - 4096) * 256 + threadIdx.x;
    if (gid < 72 * 64) {
        int frag = gid >> 6, lane = gid & 63;
        int kf = frag >> 3, s = (frag >> 2) & 1, m = frag & 3;
        int o = m * 16 + (lane & 15);
        int cb = s * 32 + (lane >> 4) * 8;
        short8 v;
#pragma unroll
        for (int j = 0; j < 8; ++j)
            v[j] = f2h(w_dcn[(o * 64 + cb + j) * 9 + kf]);
        *(short8*)(wt2 + (size_t)gid * 8) = v;
    } else {
        int g2 = gid - 72 * 64;
        if (g2 < 36 * 64) {
            int frag = g2 >> 6, lane = g2 & 63;
            int kk = frag >> 1, m = frag & 1;
            int kf = kk >> 1;
            int o = m * 16 + (lane & 15);
            int cb = (kk & 1) * 32 + (lane >> 4) * 8;
            short8 v;
#pragma unroll
            for (int j = 0; j < 8; ++j)
                v[j] = (o < 27) ? f2h(w_off[(o * 64 + cb + j) * 9 + kf]) : (short)0;
            *(short8*)(wtoff2 + (size_t)g2 * 8) = v;
        }
    }
}

// ---------------- Kernel 2: fused, LDS x-tile + pipelined corner reads ----------------
__global__ void __launch_bounds__(256, 3) fused_dcn_kernel(
        const unsigned short* __restrict__ xT,
        const unsigned short* __restrict__ wtoff2,
        const float* __restrict__ b_off,
        const unsigned short* __restrict__ wt2,
        float* __restrict__ out) {
    __shared__ char  s_x[NSLOT * 128];          // 44,160 B  [slot][chunk ^ (c&7) ^ r5]
    __shared__ float s_geo[TPX * 36];           // 9,216 B: [px][kf]{dy,dx,m,pad}

    int t = threadIdx.x;
    int blk0 = blockIdx.x;
    int blk = (blk0 & 7) * 256 + (blk0 >> 3);   // XCD swizzle (2048 = 8*256, bijective)
    int b = blk >> 8;
    int rem = blk & 255;
    int h = rem >> 1;                            // tile = 64 px of one row
    int w0 = (rem & 1) << 6;

    int lane = t & 63;
    int wv = t >> 6;
    int l15 = lane & 15;
    int g4 = lane >> 4;
    int pxl = wv * 16 + l15;                    // local pixel 0..63
    int wg = w0 + pxl;                          // global col

    const unsigned short* xTb = xT + (size_t)b * HW * 64;

    // ---- phase 0: stage x window into LDS (issue-early / write-late) ----
    {
        short8 v[11];
        int cs[11], cl[11];
#pragma unroll
        for (int it = 0; it < 11; ++it) {
            int i = it * 256 + t;
            if (i < NITEM) {
                int c_slot = i >> 3;
                cl[it] = i & 7;
                int r5 = c_slot / NC;
                int c  = c_slot - r5 * NC;
                cs[it] = c_slot;
                int row_src = min(max(h - 2 + r5, 0), 127);
                int col_src = min(max(w0 - 2 + c, 0), 127);
                v[it] = *(const short8*)(xTb + ((size_t)row_src * 128 + col_src) * 64 + cl[it] * 8);
            }
        }
#pragma unroll
        for (int it = 0; it < 11; ++it) {
            int i = it * 256 + t;
            if (i < NITEM) {
                int c_slot = cs[it];
                int r5 = c_slot / NC;
                int c = c_slot - r5 * NC;
                int baddr = c_slot * 128 + ((cl[it] ^ (c & 7) ^ r5) << 4);
                *(short8*)(s_x + baddr) = v[it];
            }
        }
    }
    __syncthreads();

    // ---- phase A: offset conv (27ch) via f16 MFMA; write packed geo {dy,dx,sig(m)} ----
    {
        f32x4 ca0 = {0.f, 0.f, 0.f, 0.f};
        f32x4 ca1 = {0.f, 0.f, 0.f, 0.f};
#pragma unroll
        for (int kk = 0; kk < 18; ++kk) {
            int kf = kk >> 1;
            int ky = kf / 3, kx = kf % 3;
            int cq = (kk & 1) * 4 + g4;
            int row = h - 1 + ky;
            int col = wg - 1 + kx;
            int cc = pxl + 1 + kx;              // window col index
            int wr = ky + 1;                    // window row 1..3
            int addr = (wr * NC + cc) * 128 + ((cq ^ (cc & 7) ^ wr) << 4);
            h8 bfrag = *(const h8*)(s_x + addr);
            if (!((unsigned)row < 128u && (unsigned)col < 128u))
                bfrag = (h8){0, 0, 0, 0, 0, 0, 0, 0};
            h8 a0 = *(const h8*)(wtoff2 + (size_t)(kk * 2 + 0) * 512 + lane * 8);
            h8 a1 = *(const h8*)(wtoff2 + (size_t)(kk * 2 + 1) * 512 + lane * 8);
            ca0 = __builtin_amdgcn_mfma_f32_16x16x32_f16(a0, bfrag, ca0, 0, 0, 0);
            ca1 = __builtin_amdgcn_mfma_f32_16x16x32_f16(a1, bfrag, ca1, 0, 0, 0);
        }
        float* gp = s_geo + pxl * 36;
        int ch0 = g4 * 4;
#pragma unroll
        for (int r = 0; r < 4; ++r) {
            int ch = ch0 + r;                   // 0..15 -> dy/dx of kf 0..7
            float v1 = ca0[r] + b_off[ch];
            gp[(ch >> 1) * 4 + (ch & 1)] = v1;
            int ch2 = 16 + ch;                  // 16..31
            if (ch2 < 18) {
                float v2 = ca1[r] + b_off[ch2];
                gp[8 * 4 + (ch2 - 16)] = v2;
            } else if (ch2 < 27) {
                float v2 = ca1[r] + b_off[ch2];
                gp[(ch2 - 18) * 4 + 2] = 1.0f / (1.0f + __expf(-v2));
            }
        }
    }
    __syncthreads();

    // ---- main loop: in-place pipelined corner reads + packed-f16 interp ----
    f32x4 acc0 = {0.f, 0.f, 0.f, 0.f};
    f32x4 acc1 = {0.f, 0.f, 0.f, 0.f};
    f32x4 acc2 = {0.f, 0.f, 0.f, 0.f};
    f32x4 acc3 = {0.f, 0.f, 0.f, 0.f};
    const f32x4* geo = (const f32x4*)(s_geo + pxl * 36);

    h8 a_cur[8], a_nxt[8];
#pragma unroll
    for (int q = 0; q < 8; ++q)
        a_cur[q] = *(const h8*)(wt2 + (size_t)q * 512 + lane * 8);

    // load_corners: geometry + issue 8 corner reads (V[0..3]=s0, V[4..7]=s1)
    auto load_corners = [&](int kf, h2* W, h8* V) {
        f32x4 g = geo[kf];
        float dy = g[0], dx = g[1], m = g[2];
        float py  = (float)(h - 1 + kf / 3) + dy;
        float pxf = (float)(wg - 1 + kf % 3) + dx;
        float y0f = floorf(py), x0f = floorf(pxf);
        float wy1 = py - y0f, wx1 = pxf - x0f;
        float wy0 = 1.f - wy1, wx0 = 1.f - wx1;
        int y0 = (int)y0f, x0 = (int)x0f;
        float ay0 = ((unsigned)y0 < 128u) ? wy0 * m : 0.f;
        float ay1 = ((unsigned)(y0 + 1) < 128u) ? wy1 * m : 0.f;
        float ax0 = ((unsigned)x0 < 128u) ? wx0 : 0.f;
        float ax1 = ((unsigned)(x0 + 1) < 128u) ? wx1 : 0.f;
        float w00 = ay0 * ax0, w01 = ay0 * ax1;
        float w10 = ay1 * ax0, w11 = ay1 * ax1;
        W[0] = (h2){(_Float16)w00, (_Float16)w00};
        W[1] = (h2){(_Float16)w01, (_Float16)w01};
        W[2] = (h2){(_Float16)w10, (_Float16)w10};
        W[3] = (h2){(_Float16)w11, (_Float16)w11};

        int r50 = y0 - (h - 2);
        int c0  = x0 - (w0 - 2);
        bool inw = (r50 >= 0) && (r50 <= 3) && (c0 >= 0) && (c0 <= 67);
        int a00 = (r50 * NC + c0) * 128;
        int a01 = a00 + 128;
        int a10 = a00 + NC * 128;
        int a11 = a10 + 128;
        int sw00 = (((c0 & 7) ^ (r50 & 7)) << 4);
        int sw01 = ((((c0 + 1) & 7) ^ (r50 & 7)) << 4);
        int sw10 = (((c0 & 7) ^ ((r50 + 1) & 7)) << 4);
        int sw11 = ((((c0 + 1) & 7) ^ ((r50 + 1) & 7)) << 4);
        if (inw) {
#pragma unroll
            for (int s = 0; s < 2; ++s) {
                int q4 = (s * 4 + g4) << 4;
                V[s * 4 + 0] = *(const h8*)(s_x + a00 + (q4 ^ sw00));
                V[s * 4 + 1] = *(const h8*)(s_x + a01 + (q4 ^ sw01));
                V[s * 4 + 2] = *(const h8*)(s_x + a10 + (q4 ^ sw10));
                V[s * 4 + 3] = *(const h8*)(s_x + a11 + (q4 ^ sw11));
            }
        } else {
            int y0c = min(max(y0, 0), 127) * 8192;
            int y1c = min(max(y0 + 1, 0), 127) * 8192;
            int x0c = min(max(x0, 0), 127) * 64;
            int x1c = min(max(x0 + 1, 0), 127) * 64;
#pragma unroll
            for (int s = 0; s < 2; ++s) {
                int cb = s * 32 + g4 * 8;
                V[s * 4 + 0] = *(const h8*)(xTb + y0c + x0c + cb);
                V[s * 4 + 1] = *(const h8*)(xTb + y0c + x1c + cb);
                V[s * 4 + 2] = *(const h8*)(xTb + y1c + x0c + cb);
                V[s * 4 + 3] = *(const h8*)(xTb + y1c + x1c + cb);
            }
        }
    };

    h2 W[4], Wn[4];
    h8 V[8];
    load_corners(0, W, V);

#pragma unroll
    for (int kf = 0; kf < 9; ++kf) {
        if (kf < 8) {
#pragma unroll
            for (int q = 0; q < 8; ++q)
                a_nxt[q] = *(const h8*)(wt2 + (size_t)((kf + 1) * 8 + q) * 512 + lane * 8);
        }

        // interp both halves (consumes V)
        h8 bf0, bf1;
        {
            const h2* p0 = (const h2*)&V[0];
            const h2* p1 = (const h2*)&V[1];
            const h2* p2 = (const h2*)&V[2];
            const h2* p3 = (const h2*)&V[3];
            h2* bp = (h2*)&bf0;
#pragma unroll
            for (int j = 0; j < 4; ++j) {
                h2 r = p3[j] * W[3];
                r = p2[j] * W[2] + r;
                r = p1[j] * W[1] + r;
                r = p0[j] * W[0] + r;
                bp[j] = r;
            }
            const h2* q0 = (const h2*)&V[4];
            const h2* q1 = (const h2*)&V[5];
            const h2* q2 = (const h2*)&V[6];
            const h2* q3 = (const h2*)&V[7];
            h2* bq = (h2*)&bf1;
#pragma unroll
            for (int j = 0; j < 4; ++j) {
                h2 r = q3[j] * W[3];
                r = q2[j] * W[2] + r;
                r = q1[j] * W[1] + r;
                r = q0[j] * W[0] + r;
                bq[j] = r;
            }
        }

        // issue next-kf corner reads while MFMAs run (in-place reuse of V)
        if (kf < 8)
            load_corners(kf + 1, Wn, V);

        __builtin_amdgcn_s_setprio(1);
        acc0 = __builtin_amdgcn_mfma_f32_16x16x32_f16(a_cur[0], bf0, acc0, 0, 0, 0);
        acc1 = __builtin_amdgcn_mfma_f32_16x16x32_f16(a_cur[1], bf0, acc1, 0, 0, 0);
        acc2 = __builtin_amdgcn_mfma_f32_16x16x32_f16(a_cur[2], bf0, acc2, 0, 0, 0);
        acc3 = __builtin_amdgcn_mfma_f32_16x16x32_f16(a_cur[3], bf0, acc3, 0, 0, 0);
        acc0 = __builtin_amdgcn_mfma_f32_16x16x32_f16(a_cur[4], bf1, acc0, 0, 0, 0);
        acc1 = __builtin_amdgcn_mfma_f32_16x16x32_f16(a_cur[5], bf1, acc1, 0, 0, 0);
        acc2 = __builtin_amdgcn_mfma_f32_16x16x32_f16(a_cur[6], bf1, acc2, 0, 0, 0);
        acc3 = __builtin_amdgcn_mfma_f32_16x16x32_f16(a_cur[7], bf1, acc3, 0, 0, 0);
        __builtin_amdgcn_s_setprio(0);

#pragma unroll
        for (int q = 0; q < 8; ++q)
            a_cur[q] = a_nxt[q];
#pragma unroll
        for (int q = 0; q < 4; ++q)
            W[q] = Wn[q];
    }

    // ---- store ----
    float* obp = out + (size_t)b * COUT * HW + (size_t)h * WW + wg;
    int or0 = g4 * 4;
#pragma unroll
    for (int r = 0; r < 4; ++r) {
        obp[(size_t)(or0 + r) * HW]      = acc0[r];
        obp[(size_t)(16 + or0 + r) * HW] = acc1[r];
        obp[(size_t)(32 + or0 + r) * HW] = acc2[r];
        obp[(size_t)(48 + or0 + r) * HW] = acc3[r];
    }
}

extern "C" void kernel_launch(void* const* d_in, const int* in_sizes, int n_in,
                              void* d_out, int out_size, void* d_ws, size_t ws_size,
                              hipStream_t stream) {
    (void)in_sizes; (void)n_in; (void)out_size; (void)ws_size;
    const float* x        = (const float*)d_in[0];
    const float* w_offset = (const float*)d_in[1];
    const float* b_offset = (const float*)d_in[2];
    const float* w_dcn    = (const float*)d_in[3];
    float* out = (float*)d_out;

    unsigned short* xT     = (unsigned short*)d_ws;                      // 16,777,216 B
    unsigned short* wt2    = (unsigned short*)((char*)d_ws + 16777216);  // 73,728 B
    unsigned short* wtoff2 = (unsigned short*)((char*)d_ws + 16850944);  // 36,864 B

    prep_kernel<<<4096 + 27, 256, 0, stream>>>(x, xT, w_dcn, w_offset, wt2, wtoff2);
    fused_dcn_kernel<<<2048, 256, 0, stream>>>(xT, wtoff2, b_offset, wt2, out);
}

// Round 14
// 55.074 us; speedup vs baseline: 1.6430x; 1.6430x over previous
//
#include <hip/hip_runtime.h>
#include <math.h>

#define BATCH 8
#define CIN 64
#define COUT 64
#define HH 128
#define WW 128
#define HW (HH*WW)
#define TPX 64       // pixels per block (half row)
#define KDIM 576
#define NR 5         // staged rows  (h-2 .. h+2, clamped)
#define NC 69        // staged cols  (w0-2 .. w0+66, clamped)
#define NSLOT (NR*NC)          // 345 col-slots
#define NITEM (NSLOT*8)        // 2760 16B-chunks

typedef __attribute__((ext_vector_type(8))) short short8;
typedef __attribute__((ext_vector_type(4))) float f32x4;
typedef _Float16 h2   __attribute__((ext_vector_type(2)));
typedef _Float16 h8   __attribute__((ext_vector_type(8)));

__device__ __forceinline__ short f2h(float f) {
    union { _Float16 h; short s; } u;
    u.h = (_Float16)f;
    return u.s;
}

// ---------------- Kernel 1: transpose + weight reorder (merged) ----------------
__global__ void __launch_bounds__(256) prep_kernel(const float* __restrict__ x,
                                                   unsigned short* __restrict__ xT,
                                                   const float* __restrict__ w_dcn,
                                                   const float* __restrict__ w_off,
                                                   unsigned short* __restrict__ wt2,
                                                   unsigned short* __restrict__ wtoff2) {
    if (blockIdx.x < 4096) {
        int idx = blockIdx.x * 256 + threadIdx.x;   // 1,048,576 total
        int c8 = idx & 7;
        int w  = (idx >> 3) & 127;
        int h  = (idx >> 10) & 127;
        int b  = idx >> 17;
        const float* xp = x + (((size_t)(b * 64 + c8 * 8) * 128 + h) * 128 + w);
        short8 o;
#pragma unroll
        for (int j = 0; j < 8; ++j)
            o[j] = f2h(xp[(size_t)j * HW]);
        *(short8*)(xT + (size_t)idx * 8) = o;
        return;
    }
    int gid = (blockIdx.x - 4096) * 256 + threadIdx.x;
    if (gid < 72 * 64) {
        int frag = gid >> 6, lane = gid & 63;
        int kf = frag >> 3, s = (frag >> 2) & 1, m = frag & 3;
        int o = m * 16 + (lane & 15);
        int cb = s * 32 + (lane >> 4) * 8;
        short8 v;
#pragma unroll
        for (int j = 0; j < 8; ++j)
            v[j] = f2h(w_dcn[(o * 64 + cb + j) * 9 + kf]);
        *(short8*)(wt2 + (size_t)gid * 8) = v;
    } else {
        int g2 = gid - 72 * 64;
        if (g2 < 36 * 64) {
            int frag = g2 >> 6, lane = g2 & 63;
            int kk = frag >> 1, m = frag & 1;
            int kf = kk >> 1;
            int o = m * 16 + (lane & 15);
            int cb = (kk & 1) * 32 + (lane >> 4) * 8;
            short8 v;
#pragma unroll
            for (int j = 0; j < 8; ++j)
                v[j] = (o < 27) ? f2h(w_off[(o * 64 + cb + j) * 9 + kf]) : (short)0;
            *(short8*)(wtoff2 + (size_t)g2 * 8) = v;
        }
    }
}

// geometry + branch-free LDS corner reads into named regs V0..V7, W0..W3
#define LOAD_CORNERS(KF)                                                    \
    do {                                                                    \
        f32x4 g = geo[(KF)];                                                \
        float dy = g[0], dxo = g[1], m = g[2];                              \
        float py  = (float)(h - 1 + (KF) / 3) + dy;                         \
        float pxf = (float)(wg - 1 + (KF) % 3) + dxo;                       \
        float y0f = floorf(py), x0f = floorf(pxf);                          \
        float wy1 = py - y0f, wx1 = pxf - x0f;                              \
        float wy0 = 1.f - wy1, wx0 = 1.f - wx1;                             \
        int y0 = (int)y0f, x0 = (int)x0f;                                   \
        int r50 = y0 - (h - 2);                                             \
        int c0  = x0 - (w0 - 2);                                            \
        bool inw = (r50 >= 0) & (r50 <= 3) & (c0 >= 0) & (c0 <= 67);        \
        float fm = inw ? m : 0.f;                                           \
        float ay0 = ((unsigned)y0 < 128u) ? wy0 * fm : 0.f;                 \
        float ay1 = ((unsigned)(y0 + 1) < 128u) ? wy1 * fm : 0.f;           \
        float ax0 = ((unsigned)x0 < 128u) ? wx0 : 0.f;                      \
        float ax1 = ((unsigned)(x0 + 1) < 128u) ? wx1 : 0.f;                \
        float w00 = ay0 * ax0, w01 = ay0 * ax1;                             \
        float w10 = ay1 * ax0, w11 = ay1 * ax1;                             \
        W0 = (h2){(_Float16)w00, (_Float16)w00};                            \
        W1 = (h2){(_Float16)w01, (_Float16)w01};                            \
        W2 = (h2){(_Float16)w10, (_Float16)w10};                            \
        W3 = (h2){(_Float16)w11, (_Float16)w11};                            \
        oow |= (inw ? 0u : 1u) << (KF);                                     \
        int r50c = min(max(r50, 0), 3);                                     \
        int c0c  = min(max(c0, 0), 67);                                     \
        int a00 = (r50c * NC + c0c) * 128;                                  \
        int a01 = a00 + 128;                                                \
        int a10 = a00 + NC * 128;                                           \
        int a11 = a10 + 128;                                                \
        int sw00 = (((c0c & 7) ^ (r50c & 7)) << 4);                         \
        int sw01 = ((((c0c + 1) & 7) ^ (r50c & 7)) << 4);                   \
        int sw10 = (((c0c & 7) ^ ((r50c + 1) & 7)) << 4);                   \
        int sw11 = ((((c0c + 1) & 7) ^ ((r50c + 1) & 7)) << 4);             \
        int q40 = g4 << 4;                                                  \
        int q41 = (4 + g4) << 4;                                            \
        V0 = *(const h8*)(s_x + a00 + (q40 ^ sw00));                        \
        V1 = *(const h8*)(s_x + a01 + (q40 ^ sw01));                        \
        V2 = *(const h8*)(s_x + a10 + (q40 ^ sw10));                        \
        V3 = *(const h8*)(s_x + a11 + (q40 ^ sw11));                        \
        V4 = *(const h8*)(s_x + a00 + (q41 ^ sw00));                        \
        V5 = *(const h8*)(s_x + a01 + (q41 ^ sw01));                        \
        V6 = *(const h8*)(s_x + a10 + (q41 ^ sw10));                        \
        V7 = *(const h8*)(s_x + a11 + (q41 ^ sw11));                        \
    } while (0)

// ---------------- Kernel 2: fused, branch-free pipelined main loop ----------------
__global__ void __launch_bounds__(256, 3) fused_dcn_kernel(
        const unsigned short* __restrict__ xT,
        const unsigned short* __restrict__ wtoff2,
        const float* __restrict__ b_off,
        const unsigned short* __restrict__ wt2,
        float* __restrict__ out) {
    __shared__ char  s_x[NSLOT * 128];          // 44,160 B  [slot][chunk ^ (c&7) ^ r5]
    __shared__ float s_geo[TPX * 36];           // 9,216 B: [px][kf]{dy,dx,m,pad}

    int t = threadIdx.x;
    int blk0 = blockIdx.x;
    int blk = (blk0 & 7) * 256 + (blk0 >> 3);   // XCD swizzle (2048 = 8*256, bijective)
    int b = blk >> 8;
    int rem = blk & 255;
    int h = rem >> 1;                            // tile = 64 px of one row
    int w0 = (rem & 1) << 6;

    int lane = t & 63;
    int wv = t >> 6;
    int l15 = lane & 15;
    int g4 = lane >> 4;
    int pxl = wv * 16 + l15;                    // local pixel 0..63
    int wg = w0 + pxl;                          // global col

    const unsigned short* xTb = xT + (size_t)b * HW * 64;

    // ---- phase 0: stage x window into LDS (issue-early / write-late) ----
    {
        short8 v[11];
        int cs[11], cl[11];
#pragma unroll
        for (int it = 0; it < 11; ++it) {
            int i = it * 256 + t;
            if (i < NITEM) {
                int c_slot = i >> 3;
                cl[it] = i & 7;
                int r5 = c_slot / NC;
                int c  = c_slot - r5 * NC;
                cs[it] = c_slot;
                int row_src = min(max(h - 2 + r5, 0), 127);
                int col_src = min(max(w0 - 2 + c, 0), 127);
                v[it] = *(const short8*)(xTb + ((size_t)row_src * 128 + col_src) * 64 + cl[it] * 8);
            }
        }
#pragma unroll
        for (int it = 0; it < 11; ++it) {
            int i = it * 256 + t;
            if (i < NITEM) {
                int c_slot = cs[it];
                int r5 = c_slot / NC;
                int c = c_slot - r5 * NC;
                int baddr = c_slot * 128 + ((cl[it] ^ (c & 7) ^ r5) << 4);
                *(short8*)(s_x + baddr) = v[it];
            }
        }
    }
    __syncthreads();

    // ---- phase A: offset conv (27ch) via f16 MFMA; write packed geo {dy,dx,sig(m)} ----
    {
        f32x4 ca0 = {0.f, 0.f, 0.f, 0.f};
        f32x4 ca1 = {0.f, 0.f, 0.f, 0.f};
#pragma unroll
        for (int kk = 0; kk < 18; ++kk) {
            int kf = kk >> 1;
            int ky = kf / 3, kx = kf % 3;
            int cq = (kk & 1) * 4 + g4;
            int row = h - 1 + ky;
            int col = wg - 1 + kx;
            int cc = pxl + 1 + kx;              // window col index
            int wr = ky + 1;                    // window row 1..3
            int addr = (wr * NC + cc) * 128 + ((cq ^ (cc & 7) ^ wr) << 4);
            h8 bfrag = *(const h8*)(s_x + addr);
            if (!((unsigned)row < 128u && (unsigned)col < 128u))
                bfrag = (h8){0, 0, 0, 0, 0, 0, 0, 0};
            h8 a0 = *(const h8*)(wtoff2 + (size_t)(kk * 2 + 0) * 512 + lane * 8);
            h8 a1 = *(const h8*)(wtoff2 + (size_t)(kk * 2 + 1) * 512 + lane * 8);
            ca0 = __builtin_amdgcn_mfma_f32_16x16x32_f16(a0, bfrag, ca0, 0, 0, 0);
            ca1 = __builtin_amdgcn_mfma_f32_16x16x32_f16(a1, bfrag, ca1, 0, 0, 0);
        }
        float* gp = s_geo + pxl * 36;
        int ch0 = g4 * 4;
#pragma unroll
        for (int r = 0; r < 4; ++r) {
            int ch = ch0 + r;                   // 0..15 -> dy/dx of kf 0..7
            float v1 = ca0[r] + b_off[ch];
            gp[(ch >> 1) * 4 + (ch & 1)] = v1;
            int ch2 = 16 + ch;                  // 16..31
            if (ch2 < 18) {
                float v2 = ca1[r] + b_off[ch2];
                gp[8 * 4 + (ch2 - 16)] = v2;
            } else if (ch2 < 27) {
                float v2 = ca1[r] + b_off[ch2];
                gp[(ch2 - 18) * 4 + 2] = 1.0f / (1.0f + __expf(-v2));
            }
        }
    }
    __syncthreads();

    // ---- main loop: branch-free, in-place pipelined ----
    f32x4 acc0 = {0.f, 0.f, 0.f, 0.f};
    f32x4 acc1 = {0.f, 0.f, 0.f, 0.f};
    f32x4 acc2 = {0.f, 0.f, 0.f, 0.f};
    f32x4 acc3 = {0.f, 0.f, 0.f, 0.f};
    const f32x4* geo = (const f32x4*)(s_geo + pxl * 36);

    h8 a_cur[8], a_nxt[8];
#pragma unroll
    for (int q = 0; q < 8; ++q)
        a_cur[q] = *(const h8*)(wt2 + (size_t)q * 512 + lane * 8);

    h8 V0, V1, V2, V3, V4, V5, V6, V7;
    h2 W0, W1, W2, W3;
    unsigned oow = 0;
    LOAD_CORNERS(0);

#pragma unroll
    for (int kf = 0; kf < 9; ++kf) {
        // interp (consumes V/W)
        h8 bf0, bf1;
        {
            const h2* p0 = (const h2*)&V0;
            const h2* p1 = (const h2*)&V1;
            const h2* p2 = (const h2*)&V2;
            const h2* p3 = (const h2*)&V3;
            h2* bp = (h2*)&bf0;
#pragma unroll
            for (int j = 0; j < 4; ++j) {
                h2 r = p3[j] * W3;
                r = p2[j] * W2 + r;
                r = p1[j] * W1 + r;
                r = p0[j] * W0 + r;
                bp[j] = r;
            }
            const h2* q0 = (const h2*)&V4;
            const h2* q1 = (const h2*)&V5;
            const h2* q2 = (const h2*)&V6;
            const h2* q3 = (const h2*)&V7;
            h2* bq = (h2*)&bf1;
#pragma unroll
            for (int j = 0; j < 4; ++j) {
                h2 r = q3[j] * W3;
                r = q2[j] * W2 + r;
                r = q1[j] * W1 + r;
                r = q0[j] * W0 + r;
                bq[j] = r;
            }
        }

        // issue next-kf corner reads + A-frag prefetch; overlaps MFMA cluster
        if (kf < 8) {
            LOAD_CORNERS(kf + 1);
#pragma unroll
            for (int q = 0; q < 8; ++q)
                a_nxt[q] = *(const h8*)(wt2 + (size_t)((kf + 1) * 8 + q) * 512 + lane * 8);
        }

        __builtin_amdgcn_s_setprio(1);
        acc0 = __builtin_amdgcn_mfma_f32_16x16x32_f16(a_cur[0], bf0, acc0, 0, 0, 0);
        acc1 = __builtin_amdgcn_mfma_f32_16x16x32_f16(a_cur[1], bf0, acc1, 0, 0, 0);
        acc2 = __builtin_amdgcn_mfma_f32_16x16x32_f16(a_cur[2], bf0, acc2, 0, 0, 0);
        acc3 = __builtin_amdgcn_mfma_f32_16x16x32_f16(a_cur[3], bf0, acc3, 0, 0, 0);
        acc0 = __builtin_amdgcn_mfma_f32_16x16x32_f16(a_cur[4], bf1, acc0, 0, 0, 0);
        acc1 = __builtin_amdgcn_mfma_f32_16x16x32_f16(a_cur[5], bf1, acc1, 0, 0, 0);
        acc2 = __builtin_amdgcn_mfma_f32_16x16x32_f16(a_cur[6], bf1, acc2, 0, 0, 0);
        acc3 = __builtin_amdgcn_mfma_f32_16x16x32_f16(a_cur[7], bf1, acc3, 0, 0, 0);
        __builtin_amdgcn_s_setprio(0);

#pragma unroll
        for (int q = 0; q < 8; ++q)
            a_cur[q] = a_nxt[q];
    }

    // ---- rare fixup: samples outside the staged window (contribution was 0) ----
    if (__builtin_expect(__any((int)(oow != 0)), 0)) {
#pragma unroll 1
        for (int kf = 0; kf < 9; ++kf) {
            if (!__any((int)((oow >> kf) & 1u))) continue;
            bool mine = (oow >> kf) & 1u;
            f32x4 g = geo[kf];
            float dy = g[0], dxo = g[1], m = g[2];
            float py  = (float)(h - 1 + kf / 3) + dy;
            float pxf = (float)(wg - 1 + kf % 3) + dxo;
            float y0f = floorf(py), x0f = floorf(pxf);
            float wy1 = py - y0f, wx1 = pxf - x0f;
            float wy0 = 1.f - wy1, wx0 = 1.f - wx1;
            int y0 = (int)y0f, x0 = (int)x0f;
            float fm = mine ? m : 0.f;
            float ay0 = ((unsigned)y0 < 128u) ? wy0 * fm : 0.f;
            float ay1 = ((unsigned)(y0 + 1) < 128u) ? wy1 * fm : 0.f;
            float ax0 = ((unsigned)x0 < 128u) ? wx0 : 0.f;
            float ax1 = ((unsigned)(x0 + 1) < 128u) ? wx1 : 0.f;
            float w00 = ay0 * ax0, w01 = ay0 * ax1;
            float w10 = ay1 * ax0, w11 = ay1 * ax1;
            h2 X0 = {(_Float16)w00, (_Float16)w00};
            h2 X1 = {(_Float16)w01, (_Float16)w01};
            h2 X2 = {(_Float16)w10, (_Float16)w10};
            h2 X3 = {(_Float16)w11, (_Float16)w11};
            int y0c = min(max(y0, 0), 127) * 8192;
            int y1c = min(max(y0 + 1, 0), 127) * 8192;
            int x0c = min(max(x0, 0), 127) * 64;
            int x1c = min(max(x0 + 1, 0), 127) * 64;
            h8 af[8];
#pragma unroll
            for (int q = 0; q < 8; ++q)
                af[q] = *(const h8*)(wt2 + (size_t)(kf * 8 + q) * 512 + lane * 8);
#pragma unroll
            for (int s = 0; s < 2; ++s) {
                int cb = s * 32 + g4 * 8;
                h8 v00 = *(const h8*)(xTb + y0c + x0c + cb);
                h8 v01 = *(const h8*)(xTb + y0c + x1c + cb);
                h8 v10 = *(const h8*)(xTb + y1c + x0c + cb);
                h8 v11 = *(const h8*)(xTb + y1c + x1c + cb);
                h8 bf;
                const h2* p0 = (const h2*)&v00;
                const h2* p1 = (const h2*)&v01;
                const h2* p2 = (const h2*)&v10;
                const h2* p3 = (const h2*)&v11;
                h2* bp = (h2*)&bf;
#pragma unroll
                for (int j = 0; j < 4; ++j) {
                    h2 r = p3[j] * X3;
                    r = p2[j] * X2 + r;
                    r = p1[j] * X1 + r;
                    r = p0[j] * X0 + r;
                    bp[j] = r;
                }
                acc0 = __builtin_amdgcn_mfma_f32_16x16x32_f16(af[s * 4 + 0], bf, acc0, 0, 0, 0);
                acc1 = __builtin_amdgcn_mfma_f32_16x16x32_f16(af[s * 4 + 1], bf, acc1, 0, 0, 0);
                acc2 = __builtin_amdgcn_mfma_f32_16x16x32_f16(af[s * 4 + 2], bf, acc2, 0, 0, 0);
                acc3 = __builtin_amdgcn_mfma_f32_16x16x32_f16(af[s * 4 + 3], bf, acc3, 0, 0, 0);
            }
        }
    }

    // ---- store ----
    float* obp = out + (size_t)b * COUT * HW + (size_t)h * WW + wg;
    int or0 = g4 * 4;
#pragma unroll
    for (int r = 0; r < 4; ++r) {
        obp[(size_t)(or0 + r) * HW]      = acc0[r];
        obp[(size_t)(16 + or0 + r) * HW] = acc1[r];
        obp[(size_t)(32 + or0 + r) * HW] = acc2[r];
        obp[(size_t)(48 + or0 + r) * HW] = acc3[r];
    }
}

extern "C" void kernel_launch(void* const* d_in, const int* in_sizes, int n_in,
                              void* d_out, int out_size, void* d_ws, size_t ws_size,
                              hipStream_t stream) {
    (void)in_sizes; (void)n_in; (void)out_size; (void)ws_size;
    const float* x        = (const float*)d_in[0];
    const float* w_offset = (const float*)d_in[1];
    const float* b_offset = (const float*)d_in[2];
    const float* w_dcn    = (const float*)d_in[3];
    float* out = (float*)d_out;

    unsigned short* xT     = (unsigned short*)d_ws;                      // 16,777,216 B
    unsigned short* wt2    = (unsigned short*)((char*)d_ws + 16777216);  // 73,728 B
    unsigned short* wtoff2 = (unsigned short*)((char*)d_ws + 16850944);  // 36,864 B

    prep_kernel<<<4096 + 27, 256, 0, stream>>>(x, xT, w_dcn, w_offset, wt2, wtoff2);
    fused_dcn_kernel<<<2048, 256, 0, stream>>>(xT, wtoff2, b_offset, wt2, out);
}